// Round 1
// baseline (142.120 us; speedup 1.0000x reference)
//
#include <hip/hip_runtime.h>

// GNNDiscriminator: fused GATConv + mean-pool + linear head.
// One block per graph (B=4096). 256 threads = 4 waves.
// Thread (wave w, lane l) owns channels c={2l,2l+1} and nodes v=8w..8w+7;
// h[v][c] lives in registers from the x@W GEMM through the final gf reduction.

#define BB   4096
#define VV   32
#define FF   16
#define NBB  8
#define CC   128
#define EPER 256
constexpr int NTOT  = BB * VV;        // 131072 nodes
constexpr int ERAND = BB * EPER;      // 1048576 random edges
constexpr int ETOT  = ERAND + NTOT;   // + self loops
constexpr float SLOPE = 0.2f;

__device__ __forceinline__ unsigned f2key(float f) {
  unsigned u = __float_as_uint(f);
  return (u & 0x80000000u) ? ~u : (u | 0x80000000u);   // order-preserving
}
__device__ __forceinline__ float key2f(unsigned k) {
  unsigned u = (k & 0x80000000u) ? (k & 0x7fffffffu) : ~k;
  return __uint_as_float(u);
}

__launch_bounds__(256, 4)
__global__ void gnn_fused(const float* __restrict__ x,
                          const int*   __restrict__ eidx,
                          const float* __restrict__ eattr,
                          const float* __restrict__ W_lin,
                          const float* __restrict__ att_src,
                          const float* __restrict__ att_dst,
                          const float* __restrict__ att_edge,
                          const float* __restrict__ W_edge,
                          const float* __restrict__ b_gat,
                          const float* __restrict__ W_out,
                          const float* __restrict__ b_out,
                          float* __restrict__ out,
                          float* __restrict__ gf_out)
{
  const int g    = blockIdx.x;
  const int t    = threadIdx.x;
  const int lane = t & 63;
  const int wave = __builtin_amdgcn_readfirstlane((int)threadIdx.x) >> 6; // uniform

  __shared__ float    s_asrc[VV], s_adst[VV];
  __shared__ unsigned s_mkey[VV];
  __shared__ float    s_denom[VV], s_inv[VV], s_r[VV];
  __shared__ float    s_we[NBB];
  __shared__ float    s_gp[4][CC];
  __shared__ float    s_gf[CC];

  if (t < VV) { s_mkey[t] = 0u; s_denom[t] = 0.f; s_r[t] = 0.f; }

  // ---- issue edge global loads early (coalesced; latency hidden under GEMM) ----
  int e_sl, e_dl;
  float4 ea0, ea1;
  {
    const int ge = g * EPER + t;            // EPER == blockDim
    e_sl = eidx[ge] - g * VV;               // local src
    e_dl = eidx[ETOT + ge] - g * VV;        // local dst
    const float4* ap = (const float4*)(eattr + (size_t)ge * NBB);
    ea0 = ap[0]; ea1 = ap[1];
  }
  float4 la0 = {0,0,0,0}, la1 = {0,0,0,0};
  if (t < VV) {                             // self-loop edge for node t
    const float4* ap = (const float4*)(eattr + (size_t)(ERAND + g * VV + t) * NBB);
    la0 = ap[0]; la1 = ap[1];
  }

  // ---- we[f] = sum_c W_edge[f][c] * att_edge[c]  (8 values, block-parallel) ----
  {
    const int f = t >> 5;                   // 0..7 across the block
    const int j = t & 31;
    float p = 0.f;
    #pragma unroll
    for (int k = 0; k < 4; ++k)
      p += W_edge[f * CC + j + 32 * k] * att_edge[j + 32 * k];
    #pragma unroll
    for (int m = 1; m <= 16; m <<= 1) p += __shfl_xor(p, m);  // reduce 32-lane group
    if (j == 0) s_we[f] = p;
  }

  // ---- h = x @ W_lin ; fused a_src/a_dst wave reductions ----
  const float2* W2 = (const float2*)W_lin;
  float2 wcol[FF];
  #pragma unroll
  for (int f = 0; f < FF; ++f) wcol[f] = W2[f * (CC / 2) + lane];  // coalesced, L1-hot
  const float2 as2 = ((const float2*)att_src)[lane];
  const float2 ad2 = ((const float2*)att_dst)[lane];

  const float* xg = x + (size_t)g * VV * FF;
  float h0[8], h1[8];
  #pragma unroll
  for (int dv = 0; dv < 8; ++dv) {
    const int v = wave * 8 + dv;            // wave-uniform -> scalar x loads
    const float* xr = xg + v * FF;
    float a0 = 0.f, a1 = 0.f;
    #pragma unroll
    for (int f = 0; f < FF; ++f) {
      const float xv = xr[f];
      a0 += xv * wcol[f].x;
      a1 += xv * wcol[f].y;
    }
    h0[dv] = a0; h1[dv] = a1;
    float ps = a0 * as2.x + a1 * as2.y;     // partial h[v] . att_src
    float pd = a0 * ad2.x + a1 * ad2.y;
    #pragma unroll
    for (int m = 1; m <= 32; m <<= 1) {
      ps += __shfl_xor(ps, m);
      pd += __shfl_xor(pd, m);
    }
    if (lane == 0) { s_asrc[v] = ps; s_adst[v] = pd; }
  }
  __syncthreads();

  // ---- edge pass 1: alpha = leaky(a_src[s]+a_dst[d]+ea.we), segment max over dst ----
  float e_alpha, l_alpha = 0.f;
  {
    const float aed = ea0.x*s_we[0] + ea0.y*s_we[1] + ea0.z*s_we[2] + ea0.w*s_we[3]
                    + ea1.x*s_we[4] + ea1.y*s_we[5] + ea1.z*s_we[6] + ea1.w*s_we[7];
    float a = s_asrc[e_sl] + s_adst[e_dl] + aed;
    e_alpha = a > 0.f ? a : SLOPE * a;
    atomicMax(&s_mkey[e_dl], f2key(e_alpha));
  }
  if (t < VV) {
    const float aed = la0.x*s_we[0] + la0.y*s_we[1] + la0.z*s_we[2] + la0.w*s_we[3]
                    + la1.x*s_we[4] + la1.y*s_we[5] + la1.z*s_we[6] + la1.w*s_we[7];
    float a = s_asrc[t] + s_adst[t] + aed;
    l_alpha = a > 0.f ? a : SLOPE * a;
    atomicMax(&s_mkey[t], f2key(l_alpha));
  }
  __syncthreads();

  // ---- edge pass 2: exp + denom (max decoded inline from key) ----
  const float e_ex = __expf(e_alpha - key2f(s_mkey[e_dl]));
  atomicAdd(&s_denom[e_dl], e_ex);
  float l_ex = 0.f;
  if (t < VV) {
    l_ex = __expf(l_alpha - key2f(s_mkey[t]));
    atomicAdd(&s_denom[t], l_ex);
  }
  __syncthreads();
  if (t < VV) s_inv[t] = 1.0f / s_denom[t];   // every node has a self loop -> denom>0
  __syncthreads();

  // ---- edge pass 3: r[s] = sum of attention weights leaving s ----
  atomicAdd(&s_r[e_sl], e_ex * s_inv[e_dl]);
  if (t < VV) atomicAdd(&s_r[t], l_ex * s_inv[t]);
  __syncthreads();

  // ---- gf[c] = (1/V) * sum_v r[v] * h[v][c] + b_gat[c]  (h still in registers) ----
  float p0 = 0.f, p1 = 0.f;
  #pragma unroll
  for (int dv = 0; dv < 8; ++dv) {
    const float rv = s_r[wave * 8 + dv];    // uniform -> LDS broadcast
    p0 += rv * h0[dv];
    p1 += rv * h1[dv];
  }
  ((float2*)(&s_gp[wave][0]))[lane] = make_float2(p0, p1);
  __syncthreads();

  if (t < CC) {
    const float gf = (s_gp[0][t] + s_gp[1][t] + s_gp[2][t] + s_gp[3][t]) * (1.0f / VV)
                   + b_gat[t];
    gf_out[(size_t)g * CC + t] = gf;
    s_gf[t] = gf;
  }
  __syncthreads();

  // ---- out[g] = gf . W_out + b_out ----
  if (t < 64) {
    float p = s_gf[t] * W_out[t] + s_gf[t + 64] * W_out[t + 64];
    #pragma unroll
    for (int m = 32; m >= 1; m >>= 1) p += __shfl_xor(p, m);
    if (t == 0) out[g] = p + b_out[0];
  }
}

extern "C" void kernel_launch(void* const* d_in, const int* in_sizes, int n_in,
                              void* d_out, int out_size, void* d_ws, size_t ws_size,
                              hipStream_t stream) {
  const float* x        = (const float*)d_in[0];
  const int*   eidx     = (const int*)  d_in[1];
  const float* eattr    = (const float*)d_in[2];
  const float* W_lin    = (const float*)d_in[3];
  const float* att_src  = (const float*)d_in[4];
  const float* att_dst  = (const float*)d_in[5];
  const float* att_edge = (const float*)d_in[6];
  const float* W_edge   = (const float*)d_in[7];
  const float* b_gat    = (const float*)d_in[8];
  const float* W_out    = (const float*)d_in[9];
  const float* b_out    = (const float*)d_in[10];

  float* out = (float*)d_out;        // [B,1] first, then gf [B,C]
  float* gf  = out + BB;

  gnn_fused<<<dim3(BB), dim3(256), 0, stream>>>(
      x, eidx, eattr, W_lin, att_src, att_dst, att_edge, W_edge,
      b_gat, W_out, b_out, out, gf);
}

// Round 2
// 128.188 us; speedup vs baseline: 1.1087x; 1.1087x over previous
//
#include <hip/hip_runtime.h>

// GNNDiscriminator: fused GATConv + mean-pool + linear head, restructured.
//
// Key identities (outputs are only (out, gf); per-node out_nodes never needed):
//   a_src[v] = x[v] . u_src,  u_src = W_lin @ att_src   (16-vec, precomputed)
//   a_dst[v] = x[v] . u_dst,  u_dst = W_lin @ att_dst
//   a_edge[e] = eattr[e] . we, we = W_edge @ att_edge   (8-vec, precomputed)
//   gf = ((r^T x) @ W_lin) / V + b_gat,  r[s] = sum of attention weights leaving s
// => no 32x16x128 GEMM per graph; just a 16-vec y = r^T x and a 16x128 matvec.
//
// One WAVE per graph (4 graphs per 256-thread block) -> zero __syncthreads;
// all cross-lane state is per-wave LDS (in-order LDS pipe within a wave).

#define BB   4096
#define VV   32
#define FF   16
#define NBB  8
#define CC   128
#define EPER 256
constexpr int NTOT  = BB * VV;
constexpr int ERAND = BB * EPER;
constexpr int ETOT  = ERAND + NTOT;
constexpr float SLOPE = 0.2f;

__device__ __forceinline__ unsigned f2key(float f) {
  unsigned u = __float_as_uint(f);
  return (u & 0x80000000u) ? ~u : (u | 0x80000000u);   // order-preserving
}
__device__ __forceinline__ float key2f(unsigned k) {
  unsigned u = (k & 0x80000000u) ? (k & 0x7fffffffu) : ~k;
  return __uint_as_float(u);
}

// ---- kernel 1: u_src[16], u_dst[16], we[8] into ws (one 64-thread block) ----
__launch_bounds__(64)
__global__ void gnn_precompute(const float* __restrict__ W_lin,
                               const float* __restrict__ att_src,
                               const float* __restrict__ att_dst,
                               const float* __restrict__ W_edge,
                               const float* __restrict__ att_edge,
                               float* __restrict__ ws)
{
  const int l = threadIdx.x;
  const float2 as = ((const float2*)att_src)[l];
  const float2 ad = ((const float2*)att_dst)[l];
  const float2 ae = ((const float2*)att_edge)[l];
  #pragma unroll
  for (int f = 0; f < FF; ++f) {
    const float2 w = ((const float2*)W_lin)[f * 64 + l];
    float ps = w.x * as.x + w.y * as.y;
    float pd = w.x * ad.x + w.y * ad.y;
    #pragma unroll
    for (int m = 1; m <= 32; m <<= 1) { ps += __shfl_xor(ps, m); pd += __shfl_xor(pd, m); }
    if (l == 0) { ws[f] = ps; ws[FF + f] = pd; }
  }
  #pragma unroll
  for (int f = 0; f < NBB; ++f) {
    const float2 w = ((const float2*)W_edge)[f * 64 + l];
    float pe = w.x * ae.x + w.y * ae.y;
    #pragma unroll
    for (int m = 1; m <= 32; m <<= 1) pe += __shfl_xor(pe, m);
    if (l == 0) ws[2 * FF + f] = pe;
  }
}

// ---- kernel 2: everything else; one wave per graph ----
__launch_bounds__(256, 4)
__global__ void gnn_main(const float* __restrict__ x,
                         const int*   __restrict__ eidx,
                         const float* __restrict__ eattr,
                         const float* __restrict__ W_lin,
                         const float* __restrict__ b_gat,
                         const float* __restrict__ W_out,
                         const float* __restrict__ b_out,
                         const float* __restrict__ ws,
                         float* __restrict__ out,
                         float* __restrict__ gf_out)
{
  const int t    = threadIdx.x;
  const int lane = t & 63;
  const int wave = __builtin_amdgcn_readfirstlane(t) >> 6;   // uniform
  const int g    = blockIdx.x * 4 + wave;

  __shared__ float    s_asrc[4][VV], s_adst[4][VV];
  __shared__ unsigned s_mkey[4][VV];
  __shared__ float    s_den[4][VV];          // denom, then 1/denom
  __shared__ float    s_r[4][VV];
  __shared__ float    s_xt[4][FF * 33];      // transposed r-scaled x, pad 33

  if (lane < VV) { s_mkey[wave][lane] = 0u; s_den[wave][lane] = 0.f; s_r[wave][lane] = 0.f; }

  // ---- edge loads: 4 random edges per lane + self-loop for lanes<32 ----
  int es[4], ed[4];
  float4 ea0[4], ea1[4];
  const int gbase = g * EPER;
  #pragma unroll
  for (int k = 0; k < 4; ++k) {
    const int ge = gbase + 64 * k + lane;
    es[k] = eidx[ge] - g * VV;
    ed[k] = eidx[ETOT + ge] - g * VV;
    const float4* ap = (const float4*)(eattr + (size_t)ge * NBB);
    ea0[k] = ap[0]; ea1[k] = ap[1];
  }
  float4 la0 = {0,0,0,0}, la1 = {0,0,0,0};
  if (lane < VV) {
    const float4* ap = (const float4*)(eattr + (size_t)(ERAND + g * VV + lane) * NBB);
    la0 = ap[0]; la1 = ap[1];
  }

  // ---- x row (lanes<32) + a_src/a_dst via precomputed u-vectors ----
  float xr[FF] = {};
  if (lane < VV) {
    const float* xp = x + (size_t)(g * VV + lane) * FF;
    #pragma unroll
    for (int f = 0; f < FF; ++f) xr[f] = xp[f];          // 4x dwordx4
    float a0 = 0.f, a1 = 0.f;
    #pragma unroll
    for (int f = 0; f < FF; ++f) { a0 += xr[f] * ws[f]; a1 += xr[f] * ws[FF + f]; }
    s_asrc[wave][lane] = a0; s_adst[wave][lane] = a1;
  }
  __threadfence_block();

  // ---- pass 1: alpha + segment max (LDS atomicMax on ordered keys) ----
  float al[5];
  #pragma unroll
  for (int k = 0; k < 4; ++k) {
    const float aed = ea0[k].x*ws[32] + ea0[k].y*ws[33] + ea0[k].z*ws[34] + ea0[k].w*ws[35]
                    + ea1[k].x*ws[36] + ea1[k].y*ws[37] + ea1[k].z*ws[38] + ea1[k].w*ws[39];
    const float a = s_asrc[wave][es[k]] + s_adst[wave][ed[k]] + aed;
    al[k] = a > 0.f ? a : SLOPE * a;
    atomicMax(&s_mkey[wave][ed[k]], f2key(al[k]));
  }
  al[4] = 0.f;
  if (lane < VV) {
    const float aed = la0.x*ws[32] + la0.y*ws[33] + la0.z*ws[34] + la0.w*ws[35]
                    + la1.x*ws[36] + la1.y*ws[37] + la1.z*ws[38] + la1.w*ws[39];
    const float a = s_asrc[wave][lane] + s_adst[wave][lane] + aed;
    al[4] = a > 0.f ? a : SLOPE * a;
    atomicMax(&s_mkey[wave][lane], f2key(al[4]));
  }
  __threadfence_block();

  // ---- pass 2: exp + denom ----
  float ex[5];
  #pragma unroll
  for (int k = 0; k < 4; ++k) {
    ex[k] = __expf(al[k] - key2f(s_mkey[wave][ed[k]]));
    atomicAdd(&s_den[wave][ed[k]], ex[k]);
  }
  ex[4] = 0.f;
  if (lane < VV) {
    ex[4] = __expf(al[4] - key2f(s_mkey[wave][lane]));
    atomicAdd(&s_den[wave][lane], ex[4]);
  }
  __threadfence_block();
  if (lane < VV) s_den[wave][lane] = 1.0f / s_den[wave][lane];  // self-loop => denom>0
  __threadfence_block();

  // ---- pass 3: r[s] = sum of outgoing attention weights ----
  #pragma unroll
  for (int k = 0; k < 4; ++k)
    atomicAdd(&s_r[wave][es[k]], ex[k] * s_den[wave][ed[k]]);
  if (lane < VV)
    atomicAdd(&s_r[wave][lane], ex[4] * s_den[wave][lane]);
  __threadfence_block();

  // ---- y = r^T x  (transposed scaled rows; all accesses <=2-way banked) ----
  if (lane < VV) {
    const float rl = s_r[wave][lane];
    #pragma unroll
    for (int f = 0; f < FF; ++f) s_xt[wave][f * 33 + lane] = xr[f] * rl;
  }
  __threadfence_block();
  const int fy = lane & 15, part = lane >> 4;
  float yp = 0.f;
  #pragma unroll
  for (int j = 0; j < 8; ++j) yp += s_xt[wave][fy * 33 + part * 8 + j];
  yp += __shfl_xor(yp, 16);
  yp += __shfl_xor(yp, 32);
  yp *= (1.0f / VV);                 // every lane now holds y[lane&15] / V

  // ---- gf = y @ W_lin + b_gat ; out = gf . W_out + b_out ----
  const float2 bg = ((const float2*)b_gat)[lane];
  float gx = bg.x, gy = bg.y;
  const float2* W2 = (const float2*)W_lin;
  #pragma unroll
  for (int f = 0; f < FF; ++f) {
    const float yf = __shfl(yp, f);                  // y[f] broadcast
    const float2 w = W2[f * 64 + lane];
    gx += yf * w.x; gy += yf * w.y;
  }
  ((float2*)(gf_out + (size_t)g * CC))[lane] = make_float2(gx, gy);

  const float2 wo = ((const float2*)W_out)[lane];
  float p = gx * wo.x + gy * wo.y;
  #pragma unroll
  for (int m = 1; m <= 32; m <<= 1) p += __shfl_xor(p, m);
  if (lane == 0) out[g] = p + b_out[0];
}

extern "C" void kernel_launch(void* const* d_in, const int* in_sizes, int n_in,
                              void* d_out, int out_size, void* d_ws, size_t ws_size,
                              hipStream_t stream) {
  const float* x        = (const float*)d_in[0];
  const int*   eidx     = (const int*)  d_in[1];
  const float* eattr    = (const float*)d_in[2];
  const float* W_lin    = (const float*)d_in[3];
  const float* att_src  = (const float*)d_in[4];
  const float* att_dst  = (const float*)d_in[5];
  const float* att_edge = (const float*)d_in[6];
  const float* W_edge   = (const float*)d_in[7];
  const float* b_gat    = (const float*)d_in[8];
  const float* W_out    = (const float*)d_in[9];
  const float* b_out    = (const float*)d_in[10];

  float* ws  = (float*)d_ws;         // [0:16) u_src, [16:32) u_dst, [32:40) we
  float* out = (float*)d_out;        // [B,1] first, then gf [B,C]
  float* gf  = out + BB;

  gnn_precompute<<<dim3(1), dim3(64), 0, stream>>>(W_lin, att_src, att_dst,
                                                   W_edge, att_edge, ws);
  gnn_main<<<dim3(BB / 4), dim3(256), 0, stream>>>(
      x, eidx, eattr, W_lin, b_gat, W_out, b_out, ws, out, gf);
}